// Round 6
// baseline (251.138 us; speedup 1.0000x reference)
//
#include <hip/hip_runtime.h>

#define NN 50000
#define NE 1600000
#define DD 64
#define RB 128                           // rows per bucket
#define NBK 391                          // ceil(NN/RB)
#define BINS 512                         // padded bin count (>= NBK)
#define EPB 4096                         // edges per sort block
#define NBLKA 391                        // ceil(NE/EPB)
#define CAP 6144                         // max edges per bucket (mean 4096, sd 64)
#define G4 800000                        // float4 groups in x
#define CONVB 196                        // convert blocks (196*1024*4 >= G4)
#define K1GRID (NBLKA + CONVB)

__device__ __forceinline__ unsigned f2bf(float f) {   // RNE
    unsigned u = __float_as_uint(f);
    u += 0x7FFFu + ((u >> 16) & 1u);
    return (u >> 16) & 0xFFFFu;
}

// ---------- K1: bucket histogram + x->bf16 convert + fused scan (last block)
__global__ __launch_bounds__(1024) void hist_conv_scan(
    const int* __restrict__ erow, int* __restrict__ gc,
    const float* __restrict__ x, uint2* __restrict__ xb,
    int* __restrict__ done)
{
    __shared__ int h[BINS];
    __shared__ int lastf;
    int tid = threadIdx.x;

    if (blockIdx.x >= NBLKA) {               // convert blocks: x -> bf16x4
        int t = (blockIdx.x - NBLKA) * 1024 + tid;
        const float4* x4 = reinterpret_cast<const float4*>(x);
        #pragma unroll
        for (int i = 0; i < 4; ++i) {
            int g = i * (CONVB * 1024) + t;
            if (g < G4) {
                float4 v = x4[g];
                uint2 o;
                o.x = f2bf(v.x) | (f2bf(v.y) << 16);
                o.y = f2bf(v.z) | (f2bf(v.w) << 16);
                xb[g] = o;
            }
        }
    } else {                                 // histogram blocks
        if (tid < BINS) h[tid] = 0;
        __syncthreads();
        int base = blockIdx.x * EPB;
        #pragma unroll
        for (int i = 0; i < 4; ++i) {
            int e = base + i * 1024 + tid;
            if (e < NE) atomicAdd(&h[erow[e] >> 7], 1);
        }
        __syncthreads();
        if (tid < BINS) { int c = h[tid]; if (c) atomicAdd(&gc[tid], c); }
    }

    // last-block-done: the final block scans the 512 bins in place
    __threadfence();
    if (tid == 0) lastf = (atomicAdd(done, 1) == K1GRID - 1);
    __syncthreads();
    if (!lastf) return;
    if (tid < 64) {
        int c[8], s = 0;
        #pragma unroll
        for (int i = 0; i < 8; ++i) { c[i] = atomicAdd(&gc[tid * 8 + i], 0); s += c[i]; }
        int v = s;
        #pragma unroll
        for (int off = 1; off < 64; off <<= 1) {
            int u = __shfl_up(v, off, 64);
            if (tid >= off) v += u;
        }
        int run = v - s;
        #pragma unroll
        for (int i = 0; i < 8; ++i) { gc[tid * 8 + i] = run; run += c[i]; }
    }
}

// ---------- K2: block-local bucket sort + contiguous-run copy-out ----------
// After this kernel gcur[b] == end offset of bucket b (start = gcur[b-1]).
// Emits split arrays: bkta[i] = (row_local<<24)|col, bktb[i] = val fp32 bits.
__global__ __launch_bounds__(1024) void bucket_scatter(
    const int* __restrict__ erow, const int* __restrict__ ecol,
    const float* __restrict__ evals,
    int* __restrict__ gcur, unsigned* __restrict__ bkta, unsigned* __restrict__ bktb)
{
    __shared__ int hist[BINS];
    __shared__ int lstart[BINS];
    __shared__ int gbase[BINS];
    __shared__ int2 data[EPB];              // 32 KB
    __shared__ unsigned short sbkt[EPB];    // 8 KB

    int tid = threadIdx.x;
    if (tid < BINS) hist[tid] = 0;
    __syncthreads();

    int base = blockIdx.x * EPB;
    int r[4], c[4], bk[4]; float v[4];
    #pragma unroll
    for (int i = 0; i < 4; ++i) {
        int e = base + i * 1024 + tid;
        if (e < NE) {
            r[i] = erow[e]; c[i] = ecol[e]; v[i] = evals[e];
            bk[i] = r[i] >> 7;
            atomicAdd(&hist[bk[i]], 1);
        } else bk[i] = -1;
    }
    __syncthreads();

    if (tid < 64) {                         // wave 0: scan 512 bins, 8/lane
        int cc[8], s = 0;
        #pragma unroll
        for (int i = 0; i < 8; ++i) { cc[i] = hist[tid * 8 + i]; s += cc[i]; }
        int vv = s;
        #pragma unroll
        for (int off = 1; off < 64; off <<= 1) {
            int u = __shfl_up(vv, off, 64);
            if (tid >= off) vv += u;
        }
        int run = vv - s;
        #pragma unroll
        for (int i = 0; i < 8; ++i) { lstart[tid * 8 + i] = run; run += cc[i]; }
    }
    __syncthreads();

    if (tid < BINS) {                       // reserve global runs; hist -> cursor
        int cnt = hist[tid];
        gbase[tid] = cnt ? atomicAdd(&gcur[tid], cnt) : 0;
        hist[tid] = lstart[tid];
    }
    __syncthreads();

    #pragma unroll
    for (int i = 0; i < 4; ++i) {           // scatter into LDS, bucket-grouped
        if (bk[i] >= 0) {
            int p = atomicAdd(&hist[bk[i]], 1);
            data[p] = make_int2(((r[i] & (RB - 1)) << 24) | c[i], __float_as_int(v[i]));
            sbkt[p] = (unsigned short)bk[i];
        }
    }
    __syncthreads();

    int total = NE - base; if (total > EPB) total = EPB;
    #pragma unroll
    for (int i = 0; i < 4; ++i) {           // coalesced copy-out of runs
        int slot = i * 1024 + tid;
        if (slot < total) {
            int bb = sbkt[slot];
            int dst = gbase[bb] + slot - lstart[bb];
            int2 d = data[slot];
            bkta[dst] = (unsigned)d.x;
            bktb[dst] = (unsigned)d.y;
        }
    }
}

// ---------- K3: row sort within bucket; emit packed (val_bf16<<16|col) ------
// Writes packed stream in place over bkta (block-exclusive range), + CSR starts.
__global__ __launch_bounds__(1024) void row_sort(
    const int* __restrict__ gcur, unsigned* bkta,
    const unsigned* __restrict__ bktb, int* __restrict__ row_start)
{
    __shared__ int rhist[RB];
    __shared__ int rpre[RB];

    int tid = threadIdx.x;
    int b = blockIdx.x;
    int bstart = (b == 0) ? 0 : gcur[b - 1];
    int bend   = gcur[b];
    int count  = bend - bstart;

    if (tid < RB) rhist[tid] = 0;
    __syncthreads();

    unsigned av[CAP / 1024], bv[CAP / 1024];
    int rl[CAP / 1024];
    #pragma unroll
    for (int i = 0; i < CAP / 1024; ++i) {
        int idx = i * 1024 + tid;
        if (idx < count) {
            av[i] = bkta[bstart + idx];
            bv[i] = bktb[bstart + idx];
            rl[i] = (av[i] >> 24) & (RB - 1);
            atomicAdd(&rhist[rl[i]], 1);
        } else rl[i] = -1;
    }
    __syncthreads();

    if (tid < 64) {                         // scan 128 bins, 2/lane
        int c0 = rhist[tid * 2], c1 = rhist[tid * 2 + 1];
        int s = c0 + c1, vv = s;
        #pragma unroll
        for (int off = 1; off < 64; off <<= 1) {
            int u = __shfl_up(vv, off, 64);
            if (tid >= off) vv += u;
        }
        int run = vv - s;
        rpre[tid * 2] = run;
        rpre[tid * 2 + 1] = run + c0;
    }
    __syncthreads();

    if (tid < RB) {                         // global CSR starts + reset cursors
        int rr = b * RB + tid;
        if (rr < NN) row_start[rr] = bstart + rpre[tid];
        rhist[tid] = rpre[tid];
    }
    if (b == NBK - 1 && tid == RB) row_start[NN] = NE;
    __syncthreads();

    int p[CAP / 1024];
    #pragma unroll
    for (int i = 0; i < CAP / 1024; ++i)
        if (rl[i] >= 0) p[i] = atomicAdd(&rhist[rl[i]], 1);
    __syncthreads();                        // all reads done before any write
    #pragma unroll
    for (int i = 0; i < CAP / 1024; ++i)
        if (rl[i] >= 0)
            bkta[bstart + p[i]] =
                (f2bf(__uint_as_float(bv[i])) << 16) | (av[i] & 0xFFFFu);
}

// ---------- K4: gather SpMM (packed CSR) + h0 mix + GEMM, no atomics --------
// out = ((1-s)*A@x + s*h0) @ (theta*W + (1-theta)*I)
__global__ __launch_bounds__(256) void spmm_gemm(
    const uint2* __restrict__ xb, const float* __restrict__ h0,
    const float* __restrict__ W,  const float* __restrict__ lamda,
    const float* __restrict__ s_ptr, const int* __restrict__ l_ptr,
    const int* __restrict__ row_start, const unsigned* __restrict__ pk,
    float* __restrict__ out)
{
    __shared__ float Wp[DD * DD];

    float theta = lamda[0] / (float)l_ptr[0];
    float s     = s_ptr[0];

    for (int i = threadIdx.x; i < DD * DD; i += 256) {
        int k = i >> 6, j = i & 63;
        float wv = theta * W[i];
        if (k == j) wv += (1.0f - theta);
        Wp[i] = wv;
    }
    __syncthreads();

    int g  = threadIdx.x >> 4;
    int f4 = threadIdx.x & 15;
    int r  = blockIdx.x * 16 + g;           // grid exact: 50000 = 3125*16

    int start = row_start[r];
    int end   = row_start[r + 1];

    float4 acc = make_float4(0.f, 0.f, 0.f, 0.f);

    #define GATHER(U)                                                       \
        {                                                                   \
            float vv = __uint_as_float((U) & 0xFFFF0000u);                  \
            uint2 q = xb[(size_t)((U) & 0xFFFFu) * 16 + f4];                \
            acc.x = fmaf(vv, __uint_as_float(q.x << 16), acc.x);            \
            acc.y = fmaf(vv, __uint_as_float(q.x & 0xFFFF0000u), acc.y);    \
            acc.z = fmaf(vv, __uint_as_float(q.y << 16), acc.z);            \
            acc.w = fmaf(vv, __uint_as_float(q.y & 0xFFFF0000u), acc.w);    \
        }

    int e = start;
    for (; e + 8 <= end; e += 8) {          // 8 independent gathers in flight
        unsigned u0 = pk[e],     u1 = pk[e + 1], u2 = pk[e + 2], u3 = pk[e + 3];
        unsigned u4 = pk[e + 4], u5 = pk[e + 5], u6 = pk[e + 6], u7 = pk[e + 7];
        GATHER(u0); GATHER(u1); GATHER(u2); GATHER(u3);
        GATHER(u4); GATHER(u5); GATHER(u6); GATHER(u7);
    }
    for (; e < end; ++e) {
        unsigned u = pk[e];
        GATHER(u);
    }
    #undef GATHER

    float4 hb = *reinterpret_cast<const float4*>(h0 + (size_t)r * DD + f4 * 4);
    float oms = 1.0f - s;
    float4 sup;
    sup.x = oms * acc.x + s * hb.x;
    sup.y = oms * acc.y + s * hb.y;
    sup.z = oms * acc.z + s * hb.z;
    sup.w = oms * acc.w + s * hb.w;

    float4 o = make_float4(0.f, 0.f, 0.f, 0.f);
    int lanebase = threadIdx.x & 48;
    #pragma unroll
    for (int k = 0; k < DD; ++k) {
        float comp = ((k & 3) == 0) ? sup.x :
                     ((k & 3) == 1) ? sup.y :
                     ((k & 3) == 2) ? sup.z : sup.w;
        float sk = __shfl(comp, lanebase + (k >> 2), 64);
        float4 w = *reinterpret_cast<const float4*>(&Wp[k * DD + f4 * 4]);
        o.x = fmaf(sk, w.x, o.x);
        o.y = fmaf(sk, w.y, o.y);
        o.z = fmaf(sk, w.z, o.z);
        o.w = fmaf(sk, w.w, o.w);
    }

    *reinterpret_cast<float4*>(out + (size_t)r * DD + f4 * 4) = o;
}

extern "C" void kernel_launch(void* const* d_in, const int* in_sizes, int n_in,
                              void* d_out, int out_size, void* d_ws, size_t ws_size,
                              hipStream_t stream) {
    const float* x     = (const float*)d_in[0];
    const float* h0    = (const float*)d_in[1];
    const float* evals = (const float*)d_in[2];
    const float* W     = (const float*)d_in[3];
    const int*   erow  = (const int*)d_in[4];
    const int*   ecol  = (const int*)d_in[5];
    const float* lamda = (const float*)d_in[6];
    const float* s_ptr = (const float*)d_in[7];
    const int*   l_ptr = (const int*)d_in[8];
    float* out = (float*)d_out;

    // ws: gcur[512]+done | row_start[NN+1] | bkta[NE] u32 | bktb[NE] u32 | xb bf16
    char* ws = (char*)d_ws;
    int*      gcur      = (int*)ws;                       // [0, 2048)
    int*      done      = (int*)(ws + BINS * 4);          // 1 int at 2048
    int*      row_start = (int*)(ws + 4096);
    size_t    bkt_off   = 4096 + (((size_t)(NN + 1) * 4 + 255) & ~(size_t)255);
    unsigned* bkta      = (unsigned*)(ws + bkt_off);
    unsigned* bktb      = bkta + NE;
    uint2*    xb        = (uint2*)(ws + bkt_off + (size_t)NE * 8);

    hipMemsetAsync(ws, 0, 4096, stream);    // zero gcur + done

    hist_conv_scan<<<K1GRID, 1024, 0, stream>>>(erow, gcur, x, xb, done);
    bucket_scatter<<<NBLKA, 1024, 0, stream>>>(erow, ecol, evals, gcur, bkta, bktb);
    row_sort      <<<NBK, 1024, 0, stream>>>(gcur, bkta, bktb, row_start);
    spmm_gemm     <<<NN / 16, 256, 0, stream>>>(xb, h0, W, lamda, s_ptr, l_ptr,
                                                row_start, bkta, out);
}

// Round 7
// 91.442 us; speedup vs baseline: 2.7464x; 2.7464x over previous
//
#include <hip/hip_runtime.h>

#define NN 50000
#define NE 1600000
#define DD 64
#define RB 128                           // rows per bucket
#define NBK 391                          // ceil(NN/RB)
#define BINS 512                         // padded bin count (>= NBK)
#define EPB 4096                         // edges per sort block
#define NBLKA 391                        // ceil(NE/EPB)
#define CAP 6144                         // max edges per bucket (mean 4096, sd 64)
#define G4 800000                        // float4 groups in x
#define CONVB 196                        // convert blocks (196*1024*4 >= G4)

__device__ __forceinline__ unsigned f2bf(float f) {   // RNE
    unsigned u = __float_as_uint(f);
    u += 0x7FFFu + ((u >> 16) & 1u);
    return (u >> 16) & 0xFFFFu;
}

// ---------- K1: bucket histogram (LDS-aggregated) + x->bf16 convert ----------
__global__ __launch_bounds__(1024) void hist_conv(
    const int* __restrict__ erow, int* __restrict__ gc,
    const float* __restrict__ x, uint2* __restrict__ xb)
{
    int tid = threadIdx.x;
    if (blockIdx.x >= NBLKA) {               // convert blocks: x -> bf16x4
        int t = (blockIdx.x - NBLKA) * 1024 + tid;
        const float4* x4 = reinterpret_cast<const float4*>(x);
        #pragma unroll
        for (int i = 0; i < 4; ++i) {
            int g = i * (CONVB * 1024) + t;
            if (g < G4) {
                float4 v = x4[g];
                uint2 o;
                o.x = f2bf(v.x) | (f2bf(v.y) << 16);
                o.y = f2bf(v.z) | (f2bf(v.w) << 16);
                xb[g] = o;
            }
        }
        return;
    }
    __shared__ int h[BINS];
    if (tid < BINS) h[tid] = 0;
    __syncthreads();
    int base = blockIdx.x * EPB;
    #pragma unroll
    for (int i = 0; i < 4; ++i) {
        int e = base + i * 1024 + tid;
        if (e < NE) atomicAdd(&h[erow[e] >> 7], 1);
    }
    __syncthreads();
    if (tid < BINS) { int c = h[tid]; if (c) atomicAdd(&gc[tid], c); }
}

// ---------- K2: exclusive scan of 512 bucket counts, one wave ----------
__global__ __launch_bounds__(64) void scan_buckets(int* __restrict__ gc)
{
    int lane = threadIdx.x;
    int c[8], s = 0;
    #pragma unroll
    for (int i = 0; i < 8; ++i) { c[i] = gc[lane * 8 + i]; s += c[i]; }
    int v = s;
    #pragma unroll
    for (int off = 1; off < 64; off <<= 1) {
        int u = __shfl_up(v, off, 64);
        if (lane >= off) v += u;
    }
    int run = v - s;
    #pragma unroll
    for (int i = 0; i < 8; ++i) { gc[lane * 8 + i] = run; run += c[i]; }
}

// ---------- K3: block-local bucket sort + contiguous-run copy-out ----------
// After this kernel gcur[b] == end offset of bucket b (start = gcur[b-1]).
// Emits split arrays: bkta[i] = (row_local<<24)|col, bktb[i] = val fp32 bits.
__global__ __launch_bounds__(1024) void bucket_scatter(
    const int* __restrict__ erow, const int* __restrict__ ecol,
    const float* __restrict__ evals,
    int* __restrict__ gcur, unsigned* __restrict__ bkta, unsigned* __restrict__ bktb)
{
    __shared__ int hist[BINS];
    __shared__ int lstart[BINS];
    __shared__ int gbase[BINS];
    __shared__ int2 data[EPB];              // 32 KB
    __shared__ unsigned short sbkt[EPB];    // 8 KB

    int tid = threadIdx.x;
    if (tid < BINS) hist[tid] = 0;
    __syncthreads();

    int base = blockIdx.x * EPB;
    int r[4], c[4], bk[4]; float v[4];
    #pragma unroll
    for (int i = 0; i < 4; ++i) {
        int e = base + i * 1024 + tid;
        if (e < NE) {
            r[i] = erow[e]; c[i] = ecol[e]; v[i] = evals[e];
            bk[i] = r[i] >> 7;
            atomicAdd(&hist[bk[i]], 1);
        } else bk[i] = -1;
    }
    __syncthreads();

    if (tid < 64) {                         // wave 0: scan 512 bins, 8/lane
        int cc[8], s = 0;
        #pragma unroll
        for (int i = 0; i < 8; ++i) { cc[i] = hist[tid * 8 + i]; s += cc[i]; }
        int vv = s;
        #pragma unroll
        for (int off = 1; off < 64; off <<= 1) {
            int u = __shfl_up(vv, off, 64);
            if (tid >= off) vv += u;
        }
        int run = vv - s;
        #pragma unroll
        for (int i = 0; i < 8; ++i) { lstart[tid * 8 + i] = run; run += cc[i]; }
    }
    __syncthreads();

    if (tid < BINS) {                       // reserve global runs; hist -> cursor
        int cnt = hist[tid];
        gbase[tid] = cnt ? atomicAdd(&gcur[tid], cnt) : 0;
        hist[tid] = lstart[tid];
    }
    __syncthreads();

    #pragma unroll
    for (int i = 0; i < 4; ++i) {           // scatter into LDS, bucket-grouped
        if (bk[i] >= 0) {
            int p = atomicAdd(&hist[bk[i]], 1);
            data[p] = make_int2(((r[i] & (RB - 1)) << 24) | c[i], __float_as_int(v[i]));
            sbkt[p] = (unsigned short)bk[i];
        }
    }
    __syncthreads();

    int total = NE - base; if (total > EPB) total = EPB;
    #pragma unroll
    for (int i = 0; i < 4; ++i) {           // coalesced copy-out of runs
        int slot = i * 1024 + tid;
        if (slot < total) {
            int bb = sbkt[slot];
            int dst = gbase[bb] + slot - lstart[bb];
            int2 d = data[slot];
            bkta[dst] = (unsigned)d.x;
            bktb[dst] = (unsigned)d.y;
        }
    }
}

// ---------- K4: row sort within bucket; emit packed (val_bf16<<16|col) ------
// Writes packed stream in place over bkta (block-exclusive range), + CSR starts.
__global__ __launch_bounds__(1024) void row_sort(
    const int* __restrict__ gcur, unsigned* bkta,
    const unsigned* __restrict__ bktb, int* __restrict__ row_start)
{
    __shared__ int rhist[RB];
    __shared__ int rpre[RB];

    int tid = threadIdx.x;
    int b = blockIdx.x;
    int bstart = (b == 0) ? 0 : gcur[b - 1];
    int bend   = gcur[b];
    int count  = bend - bstart;

    if (tid < RB) rhist[tid] = 0;
    __syncthreads();

    unsigned av[CAP / 1024], bv[CAP / 1024];
    int rl[CAP / 1024];
    #pragma unroll
    for (int i = 0; i < CAP / 1024; ++i) {
        int idx = i * 1024 + tid;
        if (idx < count) {
            av[i] = bkta[bstart + idx];
            bv[i] = bktb[bstart + idx];
            rl[i] = (av[i] >> 24) & (RB - 1);
            atomicAdd(&rhist[rl[i]], 1);
        } else rl[i] = -1;
    }
    __syncthreads();

    if (tid < 64) {                         // scan 128 bins, 2/lane
        int c0 = rhist[tid * 2], c1 = rhist[tid * 2 + 1];
        int s = c0 + c1, vv = s;
        #pragma unroll
        for (int off = 1; off < 64; off <<= 1) {
            int u = __shfl_up(vv, off, 64);
            if (tid >= off) vv += u;
        }
        int run = vv - s;
        rpre[tid * 2] = run;
        rpre[tid * 2 + 1] = run + c0;
    }
    __syncthreads();

    if (tid < RB) {                         // global CSR starts + reset cursors
        int rr = b * RB + tid;
        if (rr < NN) row_start[rr] = bstart + rpre[tid];
        rhist[tid] = rpre[tid];
    }
    if (b == NBK - 1 && tid == RB) row_start[NN] = NE;
    __syncthreads();

    int p[CAP / 1024];
    #pragma unroll
    for (int i = 0; i < CAP / 1024; ++i)
        if (rl[i] >= 0) p[i] = atomicAdd(&rhist[rl[i]], 1);
    __syncthreads();                        // all reads done before any write
    #pragma unroll
    for (int i = 0; i < CAP / 1024; ++i)
        if (rl[i] >= 0)
            bkta[bstart + p[i]] =
                (f2bf(__uint_as_float(bv[i])) << 16) | (av[i] & 0xFFFFu);
}

// ---------- K5: gather SpMM (packed CSR) + h0 mix + GEMM, no atomics --------
// out = ((1-s)*A@x + s*h0) @ (theta*W + (1-theta)*I)
__global__ __launch_bounds__(256) void spmm_gemm(
    const uint2* __restrict__ xb, const float* __restrict__ h0,
    const float* __restrict__ W,  const float* __restrict__ lamda,
    const float* __restrict__ s_ptr, const int* __restrict__ l_ptr,
    const int* __restrict__ row_start, const unsigned* __restrict__ pk,
    float* __restrict__ out)
{
    __shared__ float Wp[DD * DD];

    float theta = lamda[0] / (float)l_ptr[0];
    float s     = s_ptr[0];

    for (int i = threadIdx.x; i < DD * DD; i += 256) {
        int k = i >> 6, j = i & 63;
        float wv = theta * W[i];
        if (k == j) wv += (1.0f - theta);
        Wp[i] = wv;
    }
    __syncthreads();

    int g  = threadIdx.x >> 4;
    int f4 = threadIdx.x & 15;
    int r  = blockIdx.x * 16 + g;           // grid exact: 50000 = 3125*16

    int start = row_start[r];
    int end   = row_start[r + 1];

    float4 acc = make_float4(0.f, 0.f, 0.f, 0.f);

    #define GATHER(U)                                                       \
        {                                                                   \
            float vv = __uint_as_float((U) & 0xFFFF0000u);                  \
            uint2 q = xb[(size_t)((U) & 0xFFFFu) * 16 + f4];                \
            acc.x = fmaf(vv, __uint_as_float(q.x << 16), acc.x);            \
            acc.y = fmaf(vv, __uint_as_float(q.x & 0xFFFF0000u), acc.y);    \
            acc.z = fmaf(vv, __uint_as_float(q.y << 16), acc.z);            \
            acc.w = fmaf(vv, __uint_as_float(q.y & 0xFFFF0000u), acc.w);    \
        }

    int e = start;
    for (; e + 8 <= end; e += 8) {          // 8 independent gathers in flight
        unsigned u0 = pk[e],     u1 = pk[e + 1], u2 = pk[e + 2], u3 = pk[e + 3];
        unsigned u4 = pk[e + 4], u5 = pk[e + 5], u6 = pk[e + 6], u7 = pk[e + 7];
        GATHER(u0); GATHER(u1); GATHER(u2); GATHER(u3);
        GATHER(u4); GATHER(u5); GATHER(u6); GATHER(u7);
    }
    for (; e < end; ++e) {
        unsigned u = pk[e];
        GATHER(u);
    }
    #undef GATHER

    float4 hb = *reinterpret_cast<const float4*>(h0 + (size_t)r * DD + f4 * 4);
    float oms = 1.0f - s;
    float4 sup;
    sup.x = oms * acc.x + s * hb.x;
    sup.y = oms * acc.y + s * hb.y;
    sup.z = oms * acc.z + s * hb.z;
    sup.w = oms * acc.w + s * hb.w;

    float4 o = make_float4(0.f, 0.f, 0.f, 0.f);
    int lanebase = threadIdx.x & 48;
    #pragma unroll
    for (int k = 0; k < DD; ++k) {
        float comp = ((k & 3) == 0) ? sup.x :
                     ((k & 3) == 1) ? sup.y :
                     ((k & 3) == 2) ? sup.z : sup.w;
        float sk = __shfl(comp, lanebase + (k >> 2), 64);
        float4 w = *reinterpret_cast<const float4*>(&Wp[k * DD + f4 * 4]);
        o.x = fmaf(sk, w.x, o.x);
        o.y = fmaf(sk, w.y, o.y);
        o.z = fmaf(sk, w.z, o.z);
        o.w = fmaf(sk, w.w, o.w);
    }

    *reinterpret_cast<float4*>(out + (size_t)r * DD + f4 * 4) = o;
}

extern "C" void kernel_launch(void* const* d_in, const int* in_sizes, int n_in,
                              void* d_out, int out_size, void* d_ws, size_t ws_size,
                              hipStream_t stream) {
    const float* x     = (const float*)d_in[0];
    const float* h0    = (const float*)d_in[1];
    const float* evals = (const float*)d_in[2];
    const float* W     = (const float*)d_in[3];
    const int*   erow  = (const int*)d_in[4];
    const int*   ecol  = (const int*)d_in[5];
    const float* lamda = (const float*)d_in[6];
    const float* s_ptr = (const float*)d_in[7];
    const int*   l_ptr = (const int*)d_in[8];
    float* out = (float*)d_out;

    // ws: gcur[512] | row_start[NN+1] | bkta[NE] u32 | bktb[NE] u32 | xb bf16
    char* ws = (char*)d_ws;
    int*      gcur      = (int*)ws;                       // [0, 2048)
    int*      row_start = (int*)(ws + 4096);
    size_t    bkt_off   = 4096 + (((size_t)(NN + 1) * 4 + 255) & ~(size_t)255);
    unsigned* bkta      = (unsigned*)(ws + bkt_off);
    unsigned* bktb      = bkta + NE;
    uint2*    xb        = (uint2*)(ws + bkt_off + (size_t)NE * 8);

    hipMemsetAsync(gcur, 0, 4096, stream);  // zero gcur

    hist_conv     <<<NBLKA + CONVB, 1024, 0, stream>>>(erow, gcur, x, xb);
    scan_buckets  <<<1, 64, 0, stream>>>(gcur);
    bucket_scatter<<<NBLKA, 1024, 0, stream>>>(erow, ecol, evals, gcur, bkta, bktb);
    row_sort      <<<NBK, 1024, 0, stream>>>(gcur, bkta, bktb, row_start);
    spmm_gemm     <<<NN / 16, 256, 0, stream>>>(xb, h0, W, lamda, s_ptr, l_ptr,
                                                row_start, bkta, out);
}